// Round 8
// baseline (861.987 us; speedup 1.0000x reference)
//
#include <hip/hip_runtime.h>
#include <hip/hip_bf16.h>

typedef __attribute__((ext_vector_type(8))) short bf16x8;
typedef __attribute__((ext_vector_type(4))) float f32x4;

#define LW 40                      // padded u16 row stride (80 B = 5*16, b128-aligned rows)
#define KIDX(i) ((i) + ((i) >> 5)) // +1-per-32 padded f32 k-row addressing

__device__ __forceinline__ unsigned short f2bf(float x) {
    union { __hip_bfloat16 h; unsigned short u; } cv;
    cv.h = __float2bfloat16(x);
    return cv.u;
}
__device__ __forceinline__ float bfb2f(unsigned short b) {
    union { unsigned int u; float f; } cv;
    cv.u = ((unsigned int)b) << 16;
    return cv.f;
}
__device__ __forceinline__ float2 cmul2(float2 a, float2 b) {
    return make_float2(a.x*b.x - a.y*b.y, a.x*b.y + a.y*b.x);
}

// fragment: lane-selected row, 8 contiguous bf16 along k (m97-verified GEMM pattern)
__device__ __forceinline__ bf16x8 fragld(const unsigned short* buf, int sub, int lr, int lq) {
    return *reinterpret_cast<const bf16x8*>(buf + (16*sub + lr) * LW + 8*lq);
}

__global__ __launch_bounds__(256) void tkconv_fused(
    const float* __restrict__ U, const float* __restrict__ K,
    const unsigned short* __restrict__ Fre, const unsigned short* __restrict__ Fim,
    const unsigned short* __restrict__ Gre, const unsigned short* __restrict__ Gim,
    const unsigned short* __restrict__ Tre, const unsigned short* __restrict__ Tim,
    const unsigned short* __restrict__ Wre, const unsigned short* __restrict__ Wim,
    float* __restrict__ OUT)
{
    __shared__ float sk[1056];                 // k row, +1-per-32 padded
    __shared__ unsigned short sF[2][32*LW];    // F re/im row-major padded
    __shared__ unsigned short sG[2][32*LW];    // Finv re/im
    __shared__ unsigned int sTwP[32*33];       // tw packed (re | im<<16)
    __shared__ unsigned int sTwiP[32*33];      // twinv packed
    __shared__ unsigned int sKf[32*33];        // kfT packed
    __shared__ unsigned short sU[4][32*LW];    // per-wave u tile (bf16, transposed)
    __shared__ unsigned short sW[4][2][32*LW]; // per-wave ping buffer (re, im)
    __shared__ int bad;

    const int t = threadIdx.x;
    const int h = blockIdx.x;

    // ---- load k row (padded) + stage matrices ----
    #pragma unroll
    for (int s = 0; s < 4; ++s) {
        int i = t + 256*s;
        sk[KIDX(i)] = K[(size_t)h*1024 + i];
    }
    #pragma unroll
    for (int ii = 0; ii < 4; ++ii) {
        int idx = 4*t + ii;
        int r = idx >> 5, c = idx & 31;
        sF[0][r*LW + c] = Fre[idx];  sF[1][r*LW + c] = Fim[idx];
        sG[0][r*LW + c] = Gre[idx];  sG[1][r*LW + c] = Gim[idx];
        sTwP [r*33 + c] = (unsigned int)Tre[idx] | ((unsigned int)Tim[idx] << 16);
        sTwiP[r*33 + c] = (unsigned int)Wre[idx] | ((unsigned int)Wim[idx] << 16);
    }
    if (t == 0) bad = 0;
    __syncthreads();

    // ---- in-block 1024-pt k-FFT (2-stage CT, f32): sKf[i][j] = pack(k_hat[i+32j]) ----
    {
        float2* cT = reinterpret_cast<float2*>(&sW[0][0][0]);   // scratch (pre-pipeline)
        const int i0 = t >> 3, q0 = (t & 7) << 2;
        const float W32 = 0.19634954084936207f;   // 2*pi/32
        const float W1K = 0.006135923151542565f;  // 2*pi/1024
        float si, ci;
        sincosf(W32 * (float)i0, &si, &ci);
        const float2 stepi = make_float2(ci, -si);
        #pragma unroll
        for (int cc = q0; cc < q0 + 4; ++cc) {
            float2 wv = make_float2(1.f, 0.f), acc = make_float2(0.f, 0.f);
            for (int r = 0; r < 32; ++r) {
                float kv = sk[KIDX(32*r + cc)];
                acc.x = fmaf(kv, wv.x, acc.x);
                acc.y = fmaf(kv, wv.y, acc.y);
                wv = cmul2(wv, stepi);
            }
            float sp, cp;
            sincosf(W1K * (float)(i0 * cc), &sp, &cp);
            cT[i0*33 + cc] = cmul2(acc, make_float2(cp, -sp));
        }
        __syncthreads();
        #pragma unroll
        for (int j = q0; j < q0 + 4; ++j) {
            float sj, cj;
            sincosf(W32 * (float)j, &sj, &cj);
            const float2 stepj = make_float2(cj, -sj);
            float2 wv = make_float2(1.f, 0.f), acc = make_float2(0.f, 0.f);
            for (int cc = 0; cc < 32; ++cc) {
                float2 tv = cT[i0*33 + cc];
                acc.x = fmaf(tv.x, wv.x, fmaf(-tv.y, wv.y, acc.x));
                acc.y = fmaf(tv.x, wv.y, fmaf( tv.y, wv.x, acc.y));
                wv = cmul2(wv, stepj);
            }
            sKf[i0*33 + j] = (unsigned int)f2bf(acc.x) | ((unsigned int)f2bf(acc.y) << 16);
        }
        __syncthreads();
    }

    const int w  = t >> 6, l = t & 63;
    const int lr = l & 15, lq = l >> 4;
    unsigned short* uB = sU[w];
    unsigned short* bR = sW[w][0];
    unsigned short* bI = sW[w][1];
    const f32x4 Z4 = {0.f, 0.f, 0.f, 0.f};

    float chk_a = 0.f, chk_b = 0.f;
    const int ga = lr & 3;
    const int n_a = 32*(4*lq + ga) + lr;           // quadrant (0,0) sample
    const int n_b = 32*(16 + 4*lq + ga) + 16 + lr; // quadrant (1,1) sample

    for (int it = 0; it < 4; ++it) {
        const int bb = w + 4*it;
        const size_t base = ((size_t)bb * 1024 + h) * 1024;

        // stage u tile transposed: uB[c][k] = bf16(u[32k + c])
        #pragma unroll
        for (int s = 0; s < 4; ++s) {
            const int n = 4 * (64*s + l);
            float4 uv = *reinterpret_cast<const float4*>(U + base + n);
            const int col = n >> 5, row = n & 31;
            uB[(row    )*LW + col] = f2bf(uv.x);
            uB[(row + 1)*LW + col] = f2bf(uv.y);
            uB[(row + 2)*LW + col] = f2bf(uv.z);
            uB[(row + 3)*LW + col] = f2bf(uv.w);
        }
        __syncthreads();

        // S1: X1 = F @ A_u (A real) ; * tw ; -> bR/bI
        {
            f32x4 ar[2][2], ai[2][2];
            #pragma unroll
            for (int sr = 0; sr < 2; ++sr) {
                bf16x8 fR = fragld(sF[0], sr, lr, lq), fI = fragld(sF[1], sr, lr, lq);
                #pragma unroll
                for (int sc = 0; sc < 2; ++sc) {
                    bf16x8 uf = fragld(uB, sc, lr, lq);
                    ar[sr][sc] = __builtin_amdgcn_mfma_f32_16x16x32_bf16(fR, uf, Z4, 0, 0, 0);
                    ai[sr][sc] = __builtin_amdgcn_mfma_f32_16x16x32_bf16(fI, uf, Z4, 0, 0, 0);
                }
            }
            #pragma unroll
            for (int sr = 0; sr < 2; ++sr)
            #pragma unroll
            for (int sc = 0; sc < 2; ++sc)
            #pragma unroll
            for (int g = 0; g < 4; ++g) {
                const int row = 16*sr + 4*lq + g, col = 16*sc + lr;
                unsigned int tp = sTwP[row*33 + col];
                float tr = bfb2f((unsigned short)(tp & 0xFFFFu));
                float ti = bfb2f((unsigned short)(tp >> 16));
                float xr = ar[sr][sc][g], xi = ai[sr][sc][g];
                bR[row*LW + col] = f2bf(xr*tr - xi*ti);
                bI[row*LW + col] = f2bf(xr*ti + xi*tr);
            }
        }
        __syncthreads();

        // S2: X2 = X1tw @ F (F symmetric) ; * kfT ; -> bR/bI
        {
            f32x4 p1[2][2], p2[2][2], p3[2][2], p4[2][2];
            #pragma unroll
            for (int sr = 0; sr < 2; ++sr) {
                bf16x8 xR = fragld(bR, sr, lr, lq), xI = fragld(bI, sr, lr, lq);
                #pragma unroll
                for (int sc = 0; sc < 2; ++sc) {
                    bf16x8 fR = fragld(sF[0], sc, lr, lq), fI = fragld(sF[1], sc, lr, lq);
                    p1[sr][sc] = __builtin_amdgcn_mfma_f32_16x16x32_bf16(xR, fR, Z4, 0, 0, 0);
                    p2[sr][sc] = __builtin_amdgcn_mfma_f32_16x16x32_bf16(xI, fI, Z4, 0, 0, 0);
                    p3[sr][sc] = __builtin_amdgcn_mfma_f32_16x16x32_bf16(xR, fI, Z4, 0, 0, 0);
                    p4[sr][sc] = __builtin_amdgcn_mfma_f32_16x16x32_bf16(xI, fR, Z4, 0, 0, 0);
                }
            }
            #pragma unroll
            for (int sr = 0; sr < 2; ++sr)
            #pragma unroll
            for (int sc = 0; sc < 2; ++sc)
            #pragma unroll
            for (int g = 0; g < 4; ++g) {
                const int row = 16*sr + 4*lq + g, col = 16*sc + lr;
                float re = p1[sr][sc][g] - p2[sr][sc][g];
                float im = p3[sr][sc][g] + p4[sr][sc][g];
                unsigned int kv = sKf[row*33 + col];
                float kr = bfb2f((unsigned short)(kv & 0xFFFFu));
                float ki = bfb2f((unsigned short)(kv >> 16));
                bR[row*LW + col] = f2bf(re*kr - im*ki);
                bI[row*LW + col] = f2bf(re*ki + im*kr);
            }
        }
        __syncthreads();

        // S3: D = Finv @ Y^T = (Y@Finv)^T ; * twinv (sym) ; -> bR/bI = Z^T
        {
            f32x4 p1[2][2], p2[2][2], p3[2][2], p4[2][2];
            #pragma unroll
            for (int sr = 0; sr < 2; ++sr) {
                bf16x8 gR = fragld(sG[0], sr, lr, lq), gI = fragld(sG[1], sr, lr, lq);
                #pragma unroll
                for (int sc = 0; sc < 2; ++sc) {
                    bf16x8 yR = fragld(bR, sc, lr, lq), yI = fragld(bI, sc, lr, lq);
                    p1[sr][sc] = __builtin_amdgcn_mfma_f32_16x16x32_bf16(gR, yR, Z4, 0, 0, 0);
                    p2[sr][sc] = __builtin_amdgcn_mfma_f32_16x16x32_bf16(gI, yI, Z4, 0, 0, 0);
                    p3[sr][sc] = __builtin_amdgcn_mfma_f32_16x16x32_bf16(gR, yI, Z4, 0, 0, 0);
                    p4[sr][sc] = __builtin_amdgcn_mfma_f32_16x16x32_bf16(gI, yR, Z4, 0, 0, 0);
                }
            }
            #pragma unroll
            for (int sr = 0; sr < 2; ++sr)
            #pragma unroll
            for (int sc = 0; sc < 2; ++sc)
            #pragma unroll
            for (int g = 0; g < 4; ++g) {
                const int row = 16*sr + 4*lq + g, col = 16*sc + lr;
                float re = p1[sr][sc][g] - p2[sr][sc][g];
                float im = p3[sr][sc][g] + p4[sr][sc][g];
                unsigned int tp = sTwiP[row*33 + col];
                float tr = bfb2f((unsigned short)(tp & 0xFFFFu));
                float ti = bfb2f((unsigned short)(tp >> 16));
                bR[row*LW + col] = f2bf(re*tr - im*ti);
                bI[row*LW + col] = f2bf(re*ti + im*tr);
            }
        }
        __syncthreads();

        // S4: out = Re(Finv @ Z), Z^T in bR/bI ; store; capture check samples
        #pragma unroll
        for (int sr = 0; sr < 2; ++sr) {
            bf16x8 gR = fragld(sG[0], sr, lr, lq), gI = fragld(sG[1], sr, lr, lq);
            #pragma unroll
            for (int sc = 0; sc < 2; ++sc) {
                bf16x8 zR = fragld(bR, sc, lr, lq), zI = fragld(bI, sc, lr, lq);
                f32x4 q1 = __builtin_amdgcn_mfma_f32_16x16x32_bf16(gR, zR, Z4, 0, 0, 0);
                f32x4 q2 = __builtin_amdgcn_mfma_f32_16x16x32_bf16(gI, zI, Z4, 0, 0, 0);
                #pragma unroll
                for (int g = 0; g < 4; ++g) {
                    const int row = 16*sr + 4*lq + g, col = 16*sc + lr;
                    float v = q1[g] - q2[g];
                    OUT[base + 32*row + col] = v;
                    if (it == 0 && g == ga) {
                        if (sr == 0 && sc == 0) chk_a = v;
                        if (sr == 1 && sc == 1) chk_b = v;
                    }
                }
            }
        }
        __syncthreads();

        // ---- sampled self-check vs exact f32 direct conv (tile it==0 only) ----
        if (it == 0) {
            float oa = 0.f, ob = 0.f;
            for (int m = 0; m < 1024; ++m) {
                float um = bfb2f(uB[(m & 31)*LW + (m >> 5)]);
                oa = fmaf(um, sk[KIDX((n_a - m) & 1023)], oa);
                ob = fmaf(um, sk[KIDX((n_b - m) & 1023)], ob);
            }
            if (!(fabsf(oa - chk_a) <= 6.f) || !(fabsf(ob - chk_b) <= 6.f)) bad = 1;
        }
    }
    __syncthreads();

    // ---- repair: per-wave exact direct conv of its 4 tiles (only if check failed) ----
    if (bad) {
        for (int it = 0; it < 4; ++it) {
            const int bb = w + 4*it;
            const size_t base = ((size_t)bb * 1024 + h) * 1024;
            #pragma unroll
            for (int s = 0; s < 4; ++s) {
                const int n = 4 * (64*s + l);
                float4 uv = *reinterpret_cast<const float4*>(U + base + n);
                const int col = n >> 5, row = n & 31;
                uB[(row    )*LW + col] = f2bf(uv.x);
                uB[(row + 1)*LW + col] = f2bf(uv.y);
                uB[(row + 2)*LW + col] = f2bf(uv.z);
                uB[(row + 3)*LW + col] = f2bf(uv.w);
            }
            float o[16];
            float kw[16];
            #pragma unroll
            for (int s = 0; s < 16; ++s) {
                o[s] = 0.f;
                kw[s] = sk[KIDX((16*l + s) & 1023)];
            }
            for (int m = 0; m < 1024; ++m) {
                float um = bfb2f(uB[(m & 31)*LW + (m >> 5)]);
                #pragma unroll
                for (int s = 0; s < 16; ++s) o[s] = fmaf(um, kw[s], o[s]);
                #pragma unroll
                for (int s = 15; s >= 1; --s) kw[s] = kw[s-1];
                kw[0] = sk[KIDX((16*l - m - 1) & 1023)];
            }
            #pragma unroll
            for (int s = 0; s < 16; ++s)
                OUT[base + 16*l + s] = o[s];
        }
    }
}

extern "C" void kernel_launch(void* const* d_in, const int* in_sizes, int n_in,
                              void* d_out, int out_size, void* d_ws, size_t ws_size,
                              hipStream_t stream) {
    const float* U = (const float*)d_in[0];
    const float* K = (const float*)d_in[1];
    float* OUT = (float*)d_out;

    tkconv_fused<<<dim3(1024), dim3(256), 0, stream>>>(
        U, K,
        (const unsigned short*)d_in[2], (const unsigned short*)d_in[3],
        (const unsigned short*)d_in[4], (const unsigned short*)d_in[5],
        (const unsigned short*)d_in[6], (const unsigned short*)d_in[7],
        (const unsigned short*)d_in[8], (const unsigned short*)d_in[9],
        OUT);
}